// Round 2
// baseline (570.197 us; speedup 1.0000x reference)
//
#include <hip/hip_runtime.h>
#include <math.h>

#define T      512
#define NBATCH 512
#define IN_DIM 64
#define H      100
#define KP     208          // padded contraction: L1 = [x(64)|h1(100)|pad], L2 = [h1|h2|pad]
#define PBYTES 832          // KP*4 bytes: stride between parity buffers

typedef float f2 __attribute__((ext_vector_type(2)));

// tanh(a) = 1 - 2/(exp(2a)+1)  -- overflow-safe at both ends.
__device__ __forceinline__ float fast_tanh(float a) {
    float e = __expf(2.0f * a);
    return 1.0f - 2.0f / (e + 1.0f);
}

// ---------------------------------------------------------------------------
// v_pk_fma_f32: packed 2xf32 FMA (the instruction the 157 TF f32 peak is made
// of; scalar v_fma_f32 is half-rate, m07). Broadcast one half of va to both
// output halves via op_sel.
//   PKFMA_LO: acc.{lo,hi} += va.lo * w.{lo,hi}
//   PKFMA_HI: acc.{lo,hi} += va.hi * w.{lo,hi}
// ---------------------------------------------------------------------------
#define PKFMA_LO(acc, va, w) \
    asm("v_pk_fma_f32 %0, %1, %2, %0 op_sel:[0,0,0] op_sel_hi:[0,1,1]" \
        : "+v"(acc) : "v"(va), "v"(w));
#define PKFMA_HI(acc, va, w) \
    asm("v_pk_fma_f32 %0, %1, %2, %0 op_sel:[1,0,0] op_sel_hi:[1,1,1]" \
        : "+v"(acc) : "v"(va), "v"(w));

#define DPPMOV(x, ctrl) __int_as_float(__builtin_amdgcn_update_dpp( \
        0, __float_as_int(x), (ctrl), 0xF, 0xF, true))

// weight pair {W[R][ca], W[R][cb]} for concatenated row R:
// rows [0,kA) -> WA, [kA,kA+100) -> WB, else 0
__device__ __forceinline__ f2 wload2(const float* __restrict__ WA,
                                     const float* __restrict__ WB,
                                     int kA, int R, int ca, int cb) {
    f2 r;
    if (R < kA)             { r.x = WA[R * H + ca];  r.y = WA[R * H + cb]; }
    else {
        int rr = R - kA;
        if (rr < H)         { r.x = WB[rr * H + ca]; r.y = WB[rr * H + cb]; }
        else                { r.x = 0.f;             r.y = 0.f; }
    }
    return r;
}

// ---------------------------------------------------------------------------
// 512-thread block, one batch element. Unit = 16 lanes (K-split 16), 8 output
// cols per unit -> 4 units/wave = 32 cols/wave. 13 L1 units + 13 L2 units
// (L2 pipelined one step behind) over waves 0-6; wave 7 = x-prefetch.
// Per thread: 13 K-floats (6 f2 + 1 tail) x 8 cols = 52 f2 weight regs,
// 48 v_pk_fma_f32 + 8 scalar tail FMAs, 6 ds_read_b64 + 1 b32 per DOT.
// col(l) = (l&3)|((l>>1)&4); reduction = DPP pair-merge over lane bits
// {0,1,3} (quad_perm xor1/xor2, row_ror:8) + final xor4 (half_mirror o quad3).
// ---------------------------------------------------------------------------

#define WRDECL(r) f2 w##r##a_0={0,0}, w##r##a_1={0,0}, w##r##a_2={0,0}, w##r##a_3={0,0}, \
                     w##r##b_0={0,0}, w##r##b_1={0,0}, w##r##b_2={0,0}, w##r##b_3={0,0};

#define WRLOAD(r) { const int Ra_ = 32 * (r) + 2 * s, Rb_ = Ra_ + 1;      \
    w##r##a_0 = wload2(WA, WB, kA, Ra_, c0, c1);                          \
    w##r##a_1 = wload2(WA, WB, kA, Ra_, c2, c3);                          \
    w##r##a_2 = wload2(WA, WB, kA, Ra_, c4, c5);                          \
    w##r##a_3 = wload2(WA, WB, kA, Ra_, c6, c7);                          \
    w##r##b_0 = wload2(WA, WB, kA, Rb_, c0, c1);                          \
    w##r##b_1 = wload2(WA, WB, kA, Rb_, c2, c3);                          \
    w##r##b_2 = wload2(WA, WB, kA, Rb_, c4, c5);                          \
    w##r##b_3 = wload2(WA, WB, kA, Rb_, c6, c7); }

#define ROUND(r, P) { const f2 va_ = *(const f2*)(rb + (P) + 128 * (r));  \
    PKFMA_LO(A0, va_, w##r##a_0) PKFMA_LO(A1, va_, w##r##a_1)             \
    PKFMA_LO(A2, va_, w##r##a_2) PKFMA_LO(A3, va_, w##r##a_3)             \
    PKFMA_HI(A0, va_, w##r##b_0) PKFMA_HI(A1, va_, w##r##b_1)             \
    PKFMA_HI(A2, va_, w##r##b_2) PKFMA_HI(A3, va_, w##r##b_3) }

#define DOT(P, hv) {                                                      \
    f2 A0={0,0}, A1={0,0}, A2={0,0}, A3={0,0};                            \
    ROUND(0, P) ROUND(1, P) ROUND(2, P)                                   \
    ROUND(3, P) ROUND(4, P) ROUND(5, P)                                   \
    if (hasTail) {                                                        \
        const float vt_ = *(const float*)(tb + (P));                      \
        A0.x = fmaf(vt_, wt_0.x, A0.x); A0.y = fmaf(vt_, wt_0.y, A0.y);   \
        A1.x = fmaf(vt_, wt_1.x, A1.x); A1.y = fmaf(vt_, wt_1.y, A1.y);   \
        A2.x = fmaf(vt_, wt_2.x, A2.x); A2.y = fmaf(vt_, wt_2.y, A2.y);   \
        A3.x = fmaf(vt_, wt_3.x, A3.x); A3.y = fmaf(vt_, wt_3.y, A3.y);   \
    }                                                                     \
    /* level 1: xor1 merges col bit0 <-> lane bit0 (quad_perm) */         \
    float u0_ = (b0 ? A0.y : A0.x) + DPPMOV(b0 ? A0.x : A0.y, 0xB1);      \
    float u1_ = (b0 ? A1.y : A1.x) + DPPMOV(b0 ? A1.x : A1.y, 0xB1);      \
    float u2_ = (b0 ? A2.y : A2.x) + DPPMOV(b0 ? A2.x : A2.y, 0xB1);      \
    float u3_ = (b0 ? A3.y : A3.x) + DPPMOV(b0 ? A3.x : A3.y, 0xB1);      \
    /* level 2: xor2 merges col bit1 <-> lane bit1 */                     \
    float v0_ = (b1 ? u1_ : u0_) + DPPMOV(b1 ? u0_ : u1_, 0x4E);          \
    float v1_ = (b1 ? u3_ : u2_) + DPPMOV(b1 ? u2_ : u3_, 0x4E);          \
    /* level 3: xor8 merges col bit2 <-> lane bit3 (row_ror:8) */         \
    float z_  = (b3 ? v1_ : v0_) + DPPMOV(b3 ? v0_ : v1_, 0x128);         \
    /* level 4: xor4, same col both sides: half_mirror(^7) o quad3(^3) */ \
    z_ += DPPMOV(DPPMOV(z_, 0x141), 0x1B);                                \
    hv = fast_tanh(z_ + bj); }

__global__ __launch_bounds__(512, 4)
void drnn_kernel(const float* __restrict__ x,
                 const float* __restrict__ W1x, const float* __restrict__ W1h,
                 const float* __restrict__ b1,
                 const float* __restrict__ W2x, const float* __restrict__ W2h,
                 const float* __restrict__ b2,
                 const float* __restrict__ Wo,  const float* __restrict__ bo,
                 float* __restrict__ out)
{
    // in1: [x_t (64) | h1 (100) | pad->208]; in2: [h1 (100) | h2 (100) | pad->208]
    __shared__ __align__(16) float in1[2][KP];
    __shared__ __align__(16) float in2[2][KP];

    const int tid  = threadIdx.x;
    const int b    = blockIdx.x;
    const int lane = tid & 63;
    const int wv   = tid >> 6;
    const int s    = lane & 15;                  // K-slice within unit
    const int unit = wv * 4 + (lane >> 4);       // 16-lane unit, 0..31
    const bool active = (unit < 26);             // 13 L1 + 13 L2 units
    const bool isL1   = (unit < 13);
    const bool isXL   = (wv == 7);               // x-prefetch wave
    const bool hasTail = (wv >= 3);              // waves 0-2 pure-L1: tail rows all zero

    const float* __restrict__ xrow = x + (size_t)b * T * IN_DIM;

    // ---- zero-init LDS (pads must stay 0; h(-1)=0; h2(-1) slot stays 0) ----
    for (int k = tid; k < 2 * KP; k += 512) {
        (&in1[0][0])[k] = 0.f;
        (&in2[0][0])[k] = 0.f;
    }
    if (tid < IN_DIM) in1[0][tid] = xrow[tid];   // x(0)

    const float* __restrict__ WA = isL1 ? W1x : W2x;
    const float* __restrict__ WB = isL1 ? W1h : W2h;
    const int kA = isL1 ? IN_DIM : H;            // rows [0,kA)->WA, [kA,kA+100)->WB
    const int ul = isL1 ? unit : unit - 13;
    const int j  = 8 * ((ul >= 0 && ul < 13) ? ul : 0);     // col base, <= 96
    const int colof = (lane & 3) | ((lane >> 1) & 4);       // col-in-unit via lane bits {0,1,3}
    const int n  = j + colof;                    // output col this lane finalizes
    const bool dost = active && (n < H);         // unit 12/25 cols 100..103 masked
    const int nc = (n < H) ? n : H - 1;
    const float bj = active ? (isL1 ? b1 : b2)[nc] : 0.f;
    // clamped weight cols (padding cols load col 99, never stored)
    const int c0 = (j+0<H)?j+0:H-1, c1 = (j+1<H)?j+1:H-1, c2 = (j+2<H)?j+2:H-1, c3 = (j+3<H)?j+3:H-1;
    const int c4 = (j+4<H)?j+4:H-1, c5 = (j+5<H)?j+5:H-1, c6 = (j+6<H)?j+6:H-1, c7 = (j+7<H)?j+7:H-1;

    const bool b0 = (lane & 1) != 0;
    const bool b1_ = (lane & 2) != 0;
    const bool b3 = (lane & 8) != 0;
    #define b1 b1_

    // ---- 52 f2 weight regs (104 floats): 6 rounds x {klo,khi} x 4 colpairs + tail ----
    WRDECL(0) WRDECL(1) WRDECL(2) WRDECL(3) WRDECL(4) WRDECL(5)
    f2 wt_0={0,0}, wt_1={0,0}, wt_2={0,0}, wt_3={0,0};
    if (active) {
        WRLOAD(0) WRLOAD(1) WRLOAD(2) WRLOAD(3) WRLOAD(4) WRLOAD(5)
        const int Rt = 192 + s;
        wt_0 = wload2(WA, WB, kA, Rt, c0, c1);
        wt_1 = wload2(WA, WB, kA, Rt, c2, c3);
        wt_2 = wload2(WA, WB, kA, Rt, c4, c5);
        wt_3 = wload2(WA, WB, kA, Rt, c6, c7);
    }

    // ---- per-lane LDS pointers; odd parity reached via +PBYTES immediate ----
    const char* lb = (const char*)(isL1 ? &in1[0][0] : &in2[0][0]);
    const char* rb = lb + 8 * s;                 // round r at byte offset P + 128*r
    const char* tb = lb + 768 + 4 * s;           // tail float 192+s

    // parity-0 store slot. Duplicate col copies (lane^4) split L1's two stores.
    char* st;
    if (isL1) st = (char*)((lane & 4) ? &in2[0][n] : &in1[0][64 + n]);
    else      st = (char*)&in2[0][100 + n];      // L2 duplicates write same addr (benign)

    char* xw = (char*)&in1[0][lane];             // x slot (wave 7 only)
    float xr0 = 0.f, xr1 = 0.f;
    if (isXL) {
        xr0 = xrow[IN_DIM + lane];               // x(1)
        xr1 = xrow[2 * IN_DIM + lane];           // x(2)
    }

    __syncthreads();

    // Body i: L1 computes h1(i); L2 computes h2(i-1). Wave 7 stages x(i+1).
    #pragma unroll 1
    for (int i = 0; i < T; i += 2) {
        // ---- even body: read parity 0, write parity 1 ----
        if (active) {
            float hv; DOT(0, hv)
            if (dost && (isL1 || i > 0)) *(float*)(st + PBYTES) = hv; // skip bogus h2(-1)
        } else if (isXL) {
            *(float*)(xw + PBYTES) = xr0;        // x(i+1)
            xr0 = xr1;
            if (i + 3 < T) xr1 = xrow[(size_t)(i + 3) * IN_DIM + lane];
        }
        __syncthreads();
        // ---- odd body: read parity 1, write parity 0 ----
        if (active) {
            float hv; DOT(PBYTES, hv)
            if (dost) *(float*)st = hv;
        } else if (isXL) {
            *(float*)xw = xr0;                   // x(i+2)
            xr0 = xr1;
            if (i + 4 < T) xr1 = xrow[(size_t)(i + 4) * IN_DIM + lane];
        }
        __syncthreads();
    }

    // ---- tail (parity 0): only L2, computes h2(T-1) from {h1(T-1), h2(T-2)} ----
    if (active && !isL1) {
        float hv; DOT(0, hv)
        if (dost) *(float*)(st + PBYTES) = hv;   // -> in2[1][100..]
    }
    __syncthreads();

    // ---- epilogue: h1(T-1) in in1[0][64..], h2(T-1) in in2[1][100..] ----
    if (tid < H)
        out[NBATCH + (size_t)b * H + tid] = in1[0][64 + tid];
    if (tid < H)
        out[NBATCH + (size_t)NBATCH * H + (size_t)b * H + tid] = in2[1][100 + tid];

    // out[b] = h2_T . Wo + bo  (wave-0 shuffle reduction)
    if (tid < 64) {
        float v = in2[1][100 + tid] * Wo[tid];
        if (tid + 64 < H) v += in2[1][100 + 64 + tid] * Wo[tid + 64];
        #pragma unroll
        for (int off = 32; off >= 1; off >>= 1) v += __shfl_down(v, off);
        if (tid == 0) out[b] = v + bo[0];
    }
    #undef b1
}

extern "C" void kernel_launch(void* const* d_in, const int* in_sizes, int n_in,
                              void* d_out, int out_size, void* d_ws, size_t ws_size,
                              hipStream_t stream) {
    const float* x   = (const float*)d_in[0];
    const float* W1x = (const float*)d_in[1];
    const float* W1h = (const float*)d_in[2];
    const float* b1  = (const float*)d_in[3];
    const float* W2x = (const float*)d_in[4];
    const float* W2h = (const float*)d_in[5];
    const float* b2  = (const float*)d_in[6];
    const float* Wo  = (const float*)d_in[7];
    const float* bo  = (const float*)d_in[8];
    float* out = (float*)d_out;

    drnn_kernel<<<NBATCH, 512, 0, stream>>>(x, W1x, W1h, b1, W2x, W2h, b2,
                                            Wo, bo, out);
}